// Round 2
// baseline (686.295 us; speedup 1.0000x reference)
//
#include <hip/hip_runtime.h>

#define KC 1024   // codes
#define DD 128    // dim
#define TN 64     // rows per block
#define TK 64     // codes per k-tile
#define XSTRIDE 68  // padded row-stride for transposed X tile (16B aligned, bank-skewed)

// Prep: e2[k] = sum_d E[d][k]^2 (fp32, screening only), ET[k][d] = E[d][k].
__global__ __launch_bounds__(256) void vq_prep(const float* __restrict__ E,
                                               float* __restrict__ e2,
                                               float* __restrict__ ET) {
    int k = blockIdx.x * 256 + threadIdx.x;
    if (k >= KC) return;
    float s = 0.f;
#pragma unroll 16
    for (int d = 0; d < DD; ++d) {
        float v = E[(size_t)d * KC + k];   // coalesced over k
        ET[(size_t)k * DD + d] = v;        // tiny, L2-absorbed
        s = fmaf(v, v, s);
    }
    e2[k] = s;
}

// Fused: fp32 GEMM screening -> per-row top-2 -> fp64 rescore of 2 candidates -> gather.
__global__ __launch_bounds__(256, 2) void vq_main(const float* __restrict__ X,
                                                  const float* __restrict__ E,
                                                  const float* __restrict__ e2,
                                                  const float* __restrict__ ET,
                                                  float* __restrict__ Out,
                                                  int nrows) {
    __shared__ float  lds_x[DD * XSTRIDE];  // [d][row], 34816 B
    __shared__ float  lds_e[DD * TK];       // [d][k],   32768 B
    __shared__ float  s_x2[TN];
    __shared__ int    s_k1[TN];
    __shared__ int    s_k2[TN];
    __shared__ double s_dist[2 * TN];       // 1024 B
    __shared__ int    s_idx[TN];

    const int tid = threadIdx.x;
    const int row_base = blockIdx.x * TN;
    const int tc = tid & 15;   // k-group within tile (4 codes each)
    const int tr = tid >> 4;   // row-group (4 rows each)
    const int r0 = tr * 4;
    const int k0 = tc * 4;

    // Stage X tile transposed: coalesced global float4 along d.
    for (int i = tid; i < TN * (DD / 4); i += 256) {
        int row = i >> 5;          // DD/4 = 32
        int d4 = i & 31;
        const float4 g = *(const float4*)(X + (size_t)(row_base + row) * DD + d4 * 4);
        lds_x[(d4 * 4 + 0) * XSTRIDE + row] = g.x;
        lds_x[(d4 * 4 + 1) * XSTRIDE + row] = g.y;
        lds_x[(d4 * 4 + 2) * XSTRIDE + row] = g.z;
        lds_x[(d4 * 4 + 3) * XSTRIDE + row] = g.w;
    }
    __syncthreads();

    // ||x||^2 per row (fp32, screening only)
    if (tid < TN) {
        float s = 0.f;
#pragma unroll 16
        for (int d = 0; d < DD; ++d) {
            float v = lds_x[d * XSTRIDE + tid];
            s = fmaf(v, v, s);
        }
        s_x2[tid] = s;
    }
    __syncthreads();

    float x2r[4];
#pragma unroll
    for (int i = 0; i < 4; ++i) x2r[i] = s_x2[r0 + i];

    // per-thread top-2 (over this thread's 64 candidate codes)
    float b1d[4], b2d[4];
    int   b1k[4], b2k[4];
#pragma unroll
    for (int i = 0; i < 4; ++i) {
        b1d[i] = 3.4e38f; b2d[i] = 3.4e38f; b1k[i] = 0; b2k[i] = 0;
    }

    for (int kt = 0; kt < KC / TK; ++kt) {
        const int kbase = kt * TK;
        for (int i = tid; i < DD * (TK / 4); i += 256) {
            int d = i >> 4;        // TK/4 = 16
            int kq = i & 15;
            *(float4*)(lds_e + d * TK + kq * 4) =
                *(const float4*)(E + (size_t)d * KC + kbase + kq * 4);
        }
        __syncthreads();

        float acc[4][4];
#pragma unroll
        for (int i = 0; i < 4; ++i)
#pragma unroll
            for (int j = 0; j < 4; ++j) acc[i][j] = 0.f;

#pragma unroll 8
        for (int d = 0; d < DD; ++d) {
            const float4 a = *(const float4*)(lds_x + d * XSTRIDE + r0);
            const float4 b = *(const float4*)(lds_e + d * TK + k0);
            acc[0][0] = fmaf(a.x, b.x, acc[0][0]);
            acc[0][1] = fmaf(a.x, b.y, acc[0][1]);
            acc[0][2] = fmaf(a.x, b.z, acc[0][2]);
            acc[0][3] = fmaf(a.x, b.w, acc[0][3]);
            acc[1][0] = fmaf(a.y, b.x, acc[1][0]);
            acc[1][1] = fmaf(a.y, b.y, acc[1][1]);
            acc[1][2] = fmaf(a.y, b.z, acc[1][2]);
            acc[1][3] = fmaf(a.y, b.w, acc[1][3]);
            acc[2][0] = fmaf(a.z, b.x, acc[2][0]);
            acc[2][1] = fmaf(a.z, b.y, acc[2][1]);
            acc[2][2] = fmaf(a.z, b.z, acc[2][2]);
            acc[2][3] = fmaf(a.z, b.w, acc[2][3]);
            acc[3][0] = fmaf(a.w, b.x, acc[3][0]);
            acc[3][1] = fmaf(a.w, b.y, acc[3][1]);
            acc[3][2] = fmaf(a.w, b.z, acc[3][2]);
            acc[3][3] = fmaf(a.w, b.w, acc[3][3]);
        }

        float e2v[4];
#pragma unroll
        for (int j = 0; j < 4; ++j) e2v[j] = e2[kbase + k0 + j];

#pragma unroll
        for (int i = 0; i < 4; ++i) {
#pragma unroll
            for (int j = 0; j < 4; ++j) {
                float dist = (x2r[i] - 2.f * acc[i][j]) + e2v[j];
                int kk = kbase + k0 + j;
                if (dist < b1d[i]) {
                    b2d[i] = b1d[i]; b2k[i] = b1k[i];
                    b1d[i] = dist;   b1k[i] = kk;
                } else if (dist < b2d[i]) {
                    b2d[i] = dist; b2k[i] = kk;
                }
            }
        }
        __syncthreads();  // before next tile overwrites lds_e
    }

    // Butterfly top-2 merge across the 16 tc-lanes of each row group.
#pragma unroll
    for (int m = 1; m < 16; m <<= 1) {
#pragma unroll
        for (int i = 0; i < 4; ++i) {
            float od1 = __shfl_xor(b1d[i], m, 64);
            int   ok1 = __shfl_xor(b1k[i], m, 64);
            float od2 = __shfl_xor(b2d[i], m, 64);
            int   ok2 = __shfl_xor(b2k[i], m, 64);
            if (od1 < b1d[i] || (od1 == b1d[i] && ok1 < b1k[i])) {
                // other's first wins; my first competes for second with other's second
                float c2d = b1d[i]; int c2k = b1k[i];
                if (od2 < c2d || (od2 == c2d && ok2 < c2k)) { c2d = od2; c2k = ok2; }
                b1d[i] = od1; b1k[i] = ok1;
                b2d[i] = c2d; b2k[i] = c2k;
            } else {
                if (od1 < b2d[i] || (od1 == b2d[i] && ok1 < b2k[i])) {
                    b2d[i] = od1; b2k[i] = ok1;
                }
            }
        }
    }
    if (tc == 0) {
#pragma unroll
        for (int i = 0; i < 4; ++i) {
            s_k1[r0 + i] = b1k[i];
            s_k2[r0 + i] = b2k[i];
        }
    }
    __syncthreads();

    // fp64 rescore: 128 tasks = 64 rows x 2 candidates; exact-expansion distance.
    if (tid < 2 * TN) {
        const int row = tid >> 1;
        const int k = (tid & 1) ? s_k2[row] : s_k1[row];
        const float* __restrict__ erow = ET + (size_t)k * DD;
        double dot = 0.0, e2d = 0.0, x2d = 0.0;
#pragma unroll 8
        for (int d = 0; d < DD; ++d) {
            double xv = (double)lds_x[d * XSTRIDE + row];
            double ev = (double)erow[d];
            dot = fma(xv, ev, dot);
            e2d = fma(ev, ev, e2d);
            x2d = fma(xv, xv, x2d);
        }
        s_dist[tid] = x2d - 2.0 * dot + e2d;
    }
    __syncthreads();
    if (tid < TN) {
        double d1 = s_dist[2 * tid];
        double d2 = s_dist[2 * tid + 1];
        int k1 = s_k1[tid], k2 = s_k2[tid];
        s_idx[tid] = (d2 < d1 || (d2 == d1 && k2 < k1)) ? k2 : k1;
    }
    __syncthreads();

    // Output: out[row][:] = ET[idx[row]][:], coalesced float4 both sides.
    for (int i = tid; i < TN * (DD / 4); i += 256) {
        int row = i >> 5;
        int d4 = i & 31;
        const float4 v = *(const float4*)(ET + (size_t)s_idx[row] * DD + d4 * 4);
        *(float4*)(Out + (size_t)(row_base + row) * DD + d4 * 4) = v;
    }
}

extern "C" void kernel_launch(void* const* d_in, const int* in_sizes, int n_in,
                              void* d_out, int out_size, void* d_ws, size_t ws_size,
                              hipStream_t stream) {
    const float* X = (const float*)d_in[0];   // [N, 128]
    const float* E = (const float*)d_in[1];   // [128, 1024]
    float* Out = (float*)d_out;
    float* e2 = (float*)d_ws;                 // 1024 floats
    float* ET = e2 + KC;                      // 1024*128 floats

    const int N = in_sizes[0] / DD;           // 131072

    hipLaunchKernelGGL(vq_prep, dim3(KC / 256), dim3(256), 0, stream, E, e2, ET);
    hipLaunchKernelGGL(vq_main, dim3(N / TN), dim3(256), 0, stream,
                       X, E, e2, ET, Out, N);
}

// Round 3
// 297.767 us; speedup vs baseline: 2.3048x; 2.3048x over previous
//
#include <hip/hip_runtime.h>

#define KC 1024   // codes
#define DD 128    // dim
#define ROWS_PER_BLOCK 128   // 4 waves x 32 rows
#define NT_COUNT (KC / 16)   // 64 code-tiles of 16

typedef short bf16x8 __attribute__((ext_vector_type(8)));
typedef float f32x4  __attribute__((ext_vector_type(4)));

static __device__ __forceinline__ unsigned short f2bf(float f) {
    unsigned u = __float_as_uint(f);
    unsigned r = (u + 0x7fffu + ((u >> 16) & 1u)) >> 16;   // RNE
    return (unsigned short)r;
}
static __device__ __forceinline__ float bf2f(unsigned short h) {
    return __uint_as_float(((unsigned)h) << 16);
}

// Prep A: e2h[k] = -0.5 * sum_d E[d][k]^2 (fp32), ET[k][d] = E[d][k] (fp32).
__global__ __launch_bounds__(256) void vq_prep_e(const float* __restrict__ E,
                                                 float* __restrict__ e2h,
                                                 float* __restrict__ ET) {
    int k = blockIdx.x * 256 + threadIdx.x;
    if (k >= KC) return;
    float s = 0.f;
#pragma unroll 16
    for (int d = 0; d < DD; ++d) {
        float v = E[(size_t)d * KC + k];
        ET[(size_t)k * DD + d] = v;
        s = fmaf(v, v, s);
    }
    e2h[k] = -0.5f * s;
}

// Prep B: pack E into bf16 hi/lo MFMA B-fragments in exact lane order.
// Element idx = [nt(64)][s(4)][lane(64)][j(8)]:
//   d = s*32 + (lane>>4)*8 + j ; k = nt*16 + (lane&15)
__global__ __launch_bounds__(256) void vq_prep_pack(const float* __restrict__ E,
                                                    unsigned short* __restrict__ Bhi,
                                                    unsigned short* __restrict__ Blo) {
    int idx = blockIdx.x * 256 + threadIdx.x;   // < 64*4*64*8 = 131072
    int j    = idx & 7;
    int lane = (idx >> 3) & 63;
    int s    = (idx >> 9) & 3;
    int nt   = idx >> 11;
    int d = s * 32 + (lane >> 4) * 8 + j;
    int k = nt * 16 + (lane & 15);
    float v = E[(size_t)d * KC + k];
    unsigned short h = f2bf(v);
    unsigned short l = f2bf(v - bf2f(h));
    Bhi[idx] = h;
    Blo[idx] = l;
}

// Main: bf16-split MFMA screening (score = x.e - e^2/2, 3 products) -> per-row
// top-2 -> fp64 rescore of 2 candidates -> gather winning code row.
__global__ __launch_bounds__(256) void vq_main(const float* __restrict__ X,
                                               const float* __restrict__ e2h,
                                               const float* __restrict__ ET,
                                               const unsigned short* __restrict__ Bhi,
                                               const unsigned short* __restrict__ Blo,
                                               float* __restrict__ Out) {
    __shared__ int    s_k1[ROWS_PER_BLOCK];
    __shared__ int    s_k2[ROWS_PER_BLOCK];
    __shared__ int    s_win[ROWS_PER_BLOCK];
    __shared__ double s_d[2 * ROWS_PER_BLOCK];

    const int tid  = threadIdx.x;
    const int wave = tid >> 6;
    const int lane = tid & 63;
    const int quad = lane >> 4;
    const int n16  = lane & 15;
    const int row0 = blockIdx.x * ROWS_PER_BLOCK;         // block's first row
    const int wrow0 = row0 + wave * 32;                   // wave's first row

    // ---- A-fragments: 2 m-tiles x 4 k-steps, hi+lo, built from coalesced X reads.
    bf16x8 ahi[2][4], alo[2][4];
#pragma unroll
    for (int t = 0; t < 2; ++t) {
#pragma unroll
        for (int s = 0; s < 4; ++s) {
            const int row = wrow0 + t * 16 + n16;
            const int d0  = s * 32 + quad * 8;
            const float4 p = *(const float4*)(X + (size_t)row * DD + d0);
            const float4 q = *(const float4*)(X + (size_t)row * DD + d0 + 4);
            float v[8] = {p.x, p.y, p.z, p.w, q.x, q.y, q.z, q.w};
#pragma unroll
            for (int j = 0; j < 8; ++j) {
                unsigned short h = f2bf(v[j]);
                ahi[t][s][j] = (short)h;
                alo[t][s][j] = (short)f2bf(v[j] - bf2f(h));
            }
        }
    }

    // ---- per-lane top-2 trackers (max score, ties -> lower k)
    float b1[2][4], b2[2][4];
    int   k1[2][4], k2[2][4];
#pragma unroll
    for (int t = 0; t < 2; ++t)
#pragma unroll
        for (int r = 0; r < 4; ++r) {
            b1[t][r] = -3.4e38f; b2[t][r] = -3.4e38f;
            k1[t][r] = 0;        k2[t][r] = 0;
        }

    const bf16x8* BH = (const bf16x8*)Bhi;   // indexed in 16B fragments
    const bf16x8* BL = (const bf16x8*)Blo;

    auto loadB = [&](int nt, bf16x8* bh, bf16x8* bl, float* e2v) {
        const int base = nt * 4 * 64 + lane;
#pragma unroll
        for (int s = 0; s < 4; ++s) {
            bh[s] = BH[base + s * 64];
            bl[s] = BL[base + s * 64];
        }
        *e2v = e2h[nt * 16 + n16];
    };

    auto compute = [&](int nt, const bf16x8* bh, const bf16x8* bl, float e2v) {
        const int kk = nt * 16 + n16;
#pragma unroll
        for (int t = 0; t < 2; ++t) {
            f32x4 acc = {e2v, e2v, e2v, e2v};
#pragma unroll
            for (int s = 0; s < 4; ++s)
                acc = __builtin_amdgcn_mfma_f32_16x16x32_bf16(ahi[t][s], bh[s], acc, 0, 0, 0);
#pragma unroll
            for (int s = 0; s < 4; ++s)
                acc = __builtin_amdgcn_mfma_f32_16x16x32_bf16(alo[t][s], bh[s], acc, 0, 0, 0);
#pragma unroll
            for (int s = 0; s < 4; ++s)
                acc = __builtin_amdgcn_mfma_f32_16x16x32_bf16(ahi[t][s], bl[s], acc, 0, 0, 0);
#pragma unroll
            for (int r = 0; r < 4; ++r) {
                const float sc = acc[r];
                if (sc > b1[t][r]) {
                    b2[t][r] = b1[t][r]; k2[t][r] = k1[t][r];
                    b1[t][r] = sc;       k1[t][r] = kk;
                } else if (sc > b2[t][r]) {
                    b2[t][r] = sc; k2[t][r] = kk;
                }
            }
        }
    };

    // ---- main loop over 64 code-tiles, double-buffered B-fragments (no LDS, no barriers)
    bf16x8 bhA[4], blA[4], bhB[4], blB[4];
    float eA, eB;
    loadB(0, bhA, blA, &eA);
    for (int nt = 0; nt < NT_COUNT; nt += 2) {
        loadB(nt + 1, bhB, blB, &eB);
        compute(nt, bhA, blA, eA);
        if (nt + 2 < NT_COUNT) loadB(nt + 2, bhA, blA, &eA);
        compute(nt + 1, bhB, blB, eB);
    }

    // ---- butterfly top-2 merge across the 16 n-lanes (xor 1,2,4,8 stay in-quad)
#pragma unroll
    for (int m = 1; m < 16; m <<= 1) {
#pragma unroll
        for (int t = 0; t < 2; ++t) {
#pragma unroll
            for (int r = 0; r < 4; ++r) {
                float o1 = __shfl_xor(b1[t][r], m, 64);
                int   q1 = __shfl_xor(k1[t][r], m, 64);
                float o2 = __shfl_xor(b2[t][r], m, 64);
                int   q2 = __shfl_xor(k2[t][r], m, 64);
                bool ofirst = (o1 > b1[t][r]) || (o1 == b1[t][r] && q1 < k1[t][r]);
                if (ofirst) {
                    bool s2 = (o2 > b1[t][r]) || (o2 == b1[t][r] && q2 < k1[t][r]);
                    b2[t][r] = s2 ? o2 : b1[t][r];
                    k2[t][r] = s2 ? q2 : k1[t][r];
                    b1[t][r] = o1; k1[t][r] = q1;
                } else {
                    bool s2 = (o1 > b2[t][r]) || (o1 == b2[t][r] && q1 < k2[t][r]);
                    if (s2) { b2[t][r] = o1; k2[t][r] = q1; }
                }
            }
        }
    }
    if (n16 == 0) {
#pragma unroll
        for (int t = 0; t < 2; ++t)
#pragma unroll
            for (int r = 0; r < 4; ++r) {
                const int rr = wave * 32 + t * 16 + quad * 4 + r;
                s_k1[rr] = k1[t][r];
                s_k2[rr] = k2[t][r];
            }
    }
    __syncthreads();

    // ---- fp64 rescore: 128 rows x 2 candidates; dist = e^2 - 2*dot (x^2 constant/row)
    {
        const int row = tid >> 1;
        const int c   = tid & 1;
        const int k   = c ? s_k2[row] : s_k1[row];
        const float* __restrict__ xrow = X + (size_t)(row0 + row) * DD;
        const float* __restrict__ erow = ET + (size_t)k * DD;
        double dot = 0.0, ee = 0.0;
#pragma unroll 8
        for (int d = 0; d < DD; ++d) {
            double xv = (double)xrow[d];
            double ev = (double)erow[d];
            dot = fma(xv, ev, dot);
            ee  = fma(ev, ev, ee);
        }
        s_d[tid] = ee - 2.0 * dot;
    }
    __syncthreads();
    if (tid < ROWS_PER_BLOCK) {
        double d1 = s_d[2 * tid];
        double d2 = s_d[2 * tid + 1];
        int kk1 = s_k1[tid], kk2 = s_k2[tid];
        s_win[tid] = (d2 < d1 || (d2 == d1 && kk2 < kk1)) ? kk2 : kk1;
    }
    __syncthreads();

    // ---- gather winning code rows, coalesced float4
    for (int i = tid; i < ROWS_PER_BLOCK * (DD / 4); i += 256) {
        const int row = i >> 5;
        const int d4  = i & 31;
        const float4 v = *(const float4*)(ET + (size_t)s_win[row] * DD + d4 * 4);
        *(float4*)(Out + (size_t)(row0 + row) * DD + d4 * 4) = v;
    }
}

extern "C" void kernel_launch(void* const* d_in, const int* in_sizes, int n_in,
                              void* d_out, int out_size, void* d_ws, size_t ws_size,
                              hipStream_t stream) {
    const float* X = (const float*)d_in[0];   // [131072, 128]
    const float* E = (const float*)d_in[1];   // [128, 1024]
    float* Out = (float*)d_out;

    // workspace layout (1.03 MB total)
    float* e2h = (float*)d_ws;                                  // 1024 f
    float* ET  = e2h + KC;                                      // 131072 f
    unsigned short* Bhi = (unsigned short*)(ET + KC * DD);      // 131072 u16
    unsigned short* Blo = Bhi + KC * DD;                        // 131072 u16

    const int N = in_sizes[0] / DD;   // 131072

    hipLaunchKernelGGL(vq_prep_e, dim3(KC / 256), dim3(256), 0, stream, E, e2h, ET);
    hipLaunchKernelGGL(vq_prep_pack, dim3((KC * DD) / 256), dim3(256), 0, stream,
                       E, Bhi, Blo);
    hipLaunchKernelGGL(vq_main, dim3(N / ROWS_PER_BLOCK), dim3(256), 0, stream,
                       X, e2h, ET, Bhi, Blo, Out);
}

// Round 4
// 294.115 us; speedup vs baseline: 2.3334x; 1.0124x over previous
//
#include <hip/hip_runtime.h>

#define KC 1024   // codes
#define DD 128    // dim
#define NT_COUNT (KC / 16)   // 64 code-tiles of 16

typedef short bf16x8 __attribute__((ext_vector_type(8)));
typedef float f32x4  __attribute__((ext_vector_type(4)));

static __device__ __forceinline__ unsigned short f2bf(float f) {
    unsigned u = __float_as_uint(f);
    unsigned r = (u + 0x7fffu + ((u >> 16) & 1u)) >> 16;   // RNE
    return (unsigned short)r;
}
static __device__ __forceinline__ float bf2f(unsigned short h) {
    return __uint_as_float(((unsigned)h) << 16);
}
// monotone fp32 -> u32 map (total order preserved)
static __device__ __forceinline__ unsigned f2ord(float f) {
    unsigned u = __float_as_uint(f);
    return u ^ ((unsigned)((int)u >> 31) | 0x80000000u);
}

// ---------------- fused prep: e2h + ET + packed bf16 hi/lo B-fragments ----------------
// Bpk byte layout: [nt][hi(0)/lo(4096)][s(4)x1024][lane(64)x16][j(8)x2]
//   element (d,k): d = s*32 + (lane>>4)*8 + j ; k = nt*16 + (lane&15)
__global__ __launch_bounds__(256) void vq_prep(const float* __restrict__ E,
                                               float* __restrict__ e2h,
                                               float* __restrict__ ET,
                                               unsigned short* __restrict__ Bpk) {
    __shared__ float T[16 * 129];   // [k][d], pad 129 to spread banks
    const int nt  = blockIdx.x;     // 64 blocks, 16 codes each
    const int tid = threadIdx.x;

    // stage: coalesced over k (16 consecutive) per d
    for (int i = tid; i < 16 * DD; i += 256) {
        int d  = i >> 4;
        int kk = i & 15;
        T[kk * 129 + d] = E[(size_t)d * KC + nt * 16 + kk];
    }
    __syncthreads();

    // e2h = -0.5 * ||e_k||^2 (fp32, screening only)
    if (tid < 16) {
        float s = 0.f;
#pragma unroll 16
        for (int d = 0; d < DD; ++d) {
            float v = T[tid * 129 + d];
            s = fmaf(v, v, s);
        }
        e2h[nt * 16 + tid] = -0.5f * s;
    }

    // ET[k][d] (coalesced writes)
    for (int i = tid; i < 16 * DD; i += 256) {
        int kk = i >> 7;
        int d  = i & 127;
        ET[(size_t)(nt * 16 + kk) * DD + d] = T[kk * 129 + d];
    }

    // pack hi/lo fragments (each thread: one 16B hi frag + one 16B lo frag)
    {
        const int s    = tid >> 6;
        const int lane = tid & 63;
        const int kk   = lane & 15;
        const int d0   = s * 32 + (lane >> 4) * 8;
        bf16x8 hi, lo;
#pragma unroll
        for (int j = 0; j < 8; ++j) {
            float v = T[kk * 129 + d0 + j];
            unsigned short h = f2bf(v);
            hi[j] = (short)h;
            lo[j] = (short)f2bf(v - bf2f(h));
        }
        char* base = (char*)Bpk + (size_t)nt * 8192 + s * 1024 + lane * 16;
        *(bf16x8*)(base)        = hi;
        *(bf16x8*)(base + 4096) = lo;
    }
}

// ---------------- main: single-wave blocks, MFMA screen -> packed top-2 -> fp64 rescore ----------------
__global__ __launch_bounds__(64, 3) void vq_main(const float* __restrict__ X,
                                                 const float* __restrict__ e2h,
                                                 const float* __restrict__ ET,
                                                 const unsigned short* __restrict__ Bpk,
                                                 float* __restrict__ Out) {
    __shared__ int    s_k1[32];
    __shared__ int    s_k2[32];
    __shared__ int    s_win[32];
    __shared__ double s_d[64];

    const int lane  = threadIdx.x;   // single wave
    const int quad  = lane >> 4;
    const int n16   = lane & 15;
    const int wrow0 = blockIdx.x * 32;

    // ---- A-fragments: 2 m-tiles x 4 k-steps, hi+lo
    bf16x8 ahi[2][4], alo[2][4];
#pragma unroll
    for (int t = 0; t < 2; ++t) {
#pragma unroll
        for (int s = 0; s < 4; ++s) {
            const int row = wrow0 + t * 16 + n16;
            const int d0  = s * 32 + quad * 8;
            const float4 p = *(const float4*)(X + (size_t)row * DD + d0);
            const float4 q = *(const float4*)(X + (size_t)row * DD + d0 + 4);
            float v[8] = {p.x, p.y, p.z, p.w, q.x, q.y, q.z, q.w};
#pragma unroll
            for (int j = 0; j < 8; ++j) {
                unsigned short h = f2bf(v[j]);
                ahi[t][s][j] = (short)h;
                alo[t][s][j] = (short)f2bf(v[j] - bf2f(h));
            }
        }
    }

    // ---- packed top-2 trackers (u32: score-ordered bits with low 6 bits = 63-nt)
    unsigned p1[2][4], p2[2][4];
#pragma unroll
    for (int t = 0; t < 2; ++t)
#pragma unroll
        for (int r = 0; r < 4; ++r) { p1[t][r] = 0u; p2[t][r] = 0u; }

    const char* bp = (const char*)Bpk + (size_t)lane * 16;

    bf16x8 bhA[4], blA[4], bhB[4], blB[4];
    float eA, eB;

    auto loadB = [&](int nt, bf16x8* bh, bf16x8* bl, float* ev) {
        const char* b = bp + (size_t)nt * 8192;
#pragma unroll
        for (int s = 0; s < 4; ++s) {
            bh[s] = *(const bf16x8*)(b + s * 1024);
            bl[s] = *(const bf16x8*)(b + 4096 + s * 1024);
        }
        *ev = e2h[nt * 16 + n16];
    };

    auto compute = [&](int nt, const bf16x8* bh, const bf16x8* bl, float ev) {
        const unsigned ntinv = (unsigned)(63 - nt);
#pragma unroll
        for (int t = 0; t < 2; ++t) {
            f32x4 acc = {ev, ev, ev, ev};
#pragma unroll
            for (int s = 0; s < 4; ++s)
                acc = __builtin_amdgcn_mfma_f32_16x16x32_bf16(ahi[t][s], bh[s], acc, 0, 0, 0);
#pragma unroll
            for (int s = 0; s < 4; ++s)
                acc = __builtin_amdgcn_mfma_f32_16x16x32_bf16(alo[t][s], bh[s], acc, 0, 0, 0);
#pragma unroll
            for (int s = 0; s < 4; ++s)
                acc = __builtin_amdgcn_mfma_f32_16x16x32_bf16(ahi[t][s], bl[s], acc, 0, 0, 0);
#pragma unroll
            for (int r = 0; r < 4; ++r) {
                unsigned p = (f2ord(acc[r]) & ~63u) | ntinv;
                unsigned lo = p1[t][r] < p ? p1[t][r] : p;   // min
                p1[t][r] = p1[t][r] > p ? p1[t][r] : p;      // max
                p2[t][r] = p2[t][r] > lo ? p2[t][r] : lo;    // max
            }
        }
    };

    // ---- main loop, double-buffered, no barriers
    loadB(0, bhA, blA, &eA);
    for (int nt = 0; nt < NT_COUNT; nt += 2) {
        loadB(nt + 1, bhB, blB, &eB);
        compute(nt, bhA, blA, eA);
        if (nt + 2 < NT_COUNT) loadB(nt + 2, bhA, blA, &eA);
        compute(nt + 1, bhB, blB, eB);
    }

    // ---- re-attach full k, merge top-2 across the 16 n-lanes (u64 butterfly)
#pragma unroll
    for (int t = 0; t < 2; ++t) {
#pragma unroll
        for (int r = 0; r < 4; ++r) {
            int k1 = (int)(63u - (p1[t][r] & 63u)) * 16 + n16;
            int k2 = (int)(63u - (p2[t][r] & 63u)) * 16 + n16;
            unsigned long long q1 =
                ((unsigned long long)(p1[t][r] & ~63u) << 32) | (unsigned)(1023 - k1);
            unsigned long long q2 =
                ((unsigned long long)(p2[t][r] & ~63u) << 32) | (unsigned)(1023 - k2);
#pragma unroll
            for (int m = 1; m < 16; m <<= 1) {
                unsigned long long o1 = __shfl_xor(q1, m, 64);
                unsigned long long o2 = __shfl_xor(q2, m, 64);
                unsigned long long lo = q1 < o1 ? q1 : o1;
                q1 = q1 > o1 ? q1 : o1;
                unsigned long long hi2 = q2 > o2 ? q2 : o2;
                q2 = lo > hi2 ? lo : hi2;
            }
            if (n16 == 0) {
                int row = t * 16 + quad * 4 + r;
                s_k1[row] = 1023 - (int)(q1 & 1023u);
                s_k2[row] = 1023 - (int)(q2 & 1023u);
            }
        }
    }
    __syncthreads();

    // ---- fp64 rescore: 32 rows x 2 candidates (dist = e^2 - 2 x.e; x^2 constant/row)
    {
        const int row = lane >> 1;
        const int k   = (lane & 1) ? s_k2[row] : s_k1[row];
        const float* __restrict__ xrow = X + (size_t)(wrow0 + row) * DD;
        const float* __restrict__ erow = ET + (size_t)k * DD;
        double dot = 0.0, ee = 0.0;
#pragma unroll 8
        for (int d = 0; d < DD; ++d) {
            double xv = (double)xrow[d];
            double evd = (double)erow[d];
            dot = fma(xv, evd, dot);
            ee  = fma(evd, evd, ee);
        }
        s_d[lane] = ee - 2.0 * dot;
    }
    __syncthreads();
    if (lane < 32) {
        double d1 = s_d[2 * lane];
        double d2 = s_d[2 * lane + 1];
        int kk1 = s_k1[lane], kk2 = s_k2[lane];
        s_win[lane] = (d2 < d1 || (d2 == d1 && kk2 < kk1)) ? kk2 : kk1;
    }
    __syncthreads();

    // ---- gather winning code rows (exact fp32 copies), coalesced float4
    for (int i = lane; i < 32 * (DD / 4); i += 64) {
        const int row = i >> 5;
        const int d4  = i & 31;
        const float4 v = *(const float4*)(ET + (size_t)s_win[row] * DD + d4 * 4);
        *(float4*)(Out + (size_t)(wrow0 + row) * DD + d4 * 4) = v;
    }
}

extern "C" void kernel_launch(void* const* d_in, const int* in_sizes, int n_in,
                              void* d_out, int out_size, void* d_ws, size_t ws_size,
                              hipStream_t stream) {
    const float* X = (const float*)d_in[0];   // [131072, 128]
    const float* E = (const float*)d_in[1];   // [128, 1024]
    float* Out = (float*)d_out;

    // workspace: e2h (4 KB) | ET (512 KB) | Bpk (512 KB)
    float* e2h = (float*)d_ws;
    float* ET  = e2h + KC;
    unsigned short* Bpk = (unsigned short*)(ET + (size_t)KC * DD);

    const int N = in_sizes[0] / DD;   // 131072

    hipLaunchKernelGGL(vq_prep, dim3(NT_COUNT), dim3(256), 0, stream, E, e2h, ET, Bpk);
    hipLaunchKernelGGL(vq_main, dim3(N / 32), dim3(64), 0, stream,
                       X, e2h, ET, Bpk, Out);
}

// Round 5
// 248.967 us; speedup vs baseline: 2.7566x; 1.1813x over previous
//
#include <hip/hip_runtime.h>

#define KC 1024   // codes
#define DD 128    // dim
#define NT_COUNT (KC / 16)   // 64 code-tiles of 16

typedef short bf16x8 __attribute__((ext_vector_type(8)));
typedef float f32x4  __attribute__((ext_vector_type(4)));

#define AS1 __attribute__((address_space(1)))
#define AS3 __attribute__((address_space(3)))

static __device__ __forceinline__ unsigned short f2bf(float f) {
    unsigned u = __float_as_uint(f);
    unsigned r = (u + 0x7fffu + ((u >> 16) & 1u)) >> 16;   // RNE
    return (unsigned short)r;
}
static __device__ __forceinline__ float bf2f(unsigned short h) {
    return __uint_as_float(((unsigned)h) << 16);
}
static __device__ __forceinline__ void gl_lds16(const void* g, void* l) {
    __builtin_amdgcn_global_load_lds((const AS1 void*)g, (AS3 void*)l, 16, 0, 0);
}
static __device__ __forceinline__ void gl_lds4(const void* g, void* l) {
    __builtin_amdgcn_global_load_lds((const AS1 void*)g, (AS3 void*)l, 4, 0, 0);
}

// ---------------- fused prep: e2h (+512 offset) + ET + packed bf16 hi/lo B-fragments ----------------
// Bpk byte layout: [nt][c(8)x1024][lane(64)x16]; c<4 = hi s=c, c>=4 = lo s=c-4.
//   element (d,k): d = s*32 + (lane>>4)*8 + j ; k = nt*16 + (lane&15)
__global__ __launch_bounds__(256) void vq_prep(const float* __restrict__ E,
                                               float* __restrict__ e2h,
                                               float* __restrict__ ET,
                                               unsigned short* __restrict__ Bpk) {
    __shared__ float T[16 * 129];   // [k][d]
    const int nt  = blockIdx.x;     // 64 blocks, 16 codes each
    const int tid = threadIdx.x;

    for (int i = tid; i < 16 * DD; i += 256) {
        int d  = i >> 4;
        int kk = i & 15;
        T[kk * 129 + d] = E[(size_t)d * KC + nt * 16 + kk];
    }
    __syncthreads();

    // e2h = 512 - 0.5*||e_k||^2 (offset keeps all screen scores positive)
    if (tid < 16) {
        float s = 0.f;
#pragma unroll 16
        for (int d = 0; d < DD; ++d) {
            float v = T[tid * 129 + d];
            s = fmaf(v, v, s);
        }
        e2h[nt * 16 + tid] = 512.0f - 0.5f * s;
    }

    for (int i = tid; i < 16 * DD; i += 256) {
        int kk = i >> 7;
        int d  = i & 127;
        ET[(size_t)(nt * 16 + kk) * DD + d] = T[kk * 129 + d];
    }

    {
        const int s    = tid >> 6;
        const int lane = tid & 63;
        const int kk   = lane & 15;
        const int d0   = s * 32 + (lane >> 4) * 8;
        bf16x8 hi, lo;
#pragma unroll
        for (int j = 0; j < 8; ++j) {
            float v = T[kk * 129 + d0 + j];
            unsigned short h = f2bf(v);
            hi[j] = (short)h;
            lo[j] = (short)f2bf(v - bf2f(h));
        }
        char* base = (char*)Bpk + (size_t)nt * 8192 + s * 1024 + lane * 16;
        *(bf16x8*)(base)        = hi;
        *(bf16x8*)(base + 4096) = lo;
    }
}

// ---------------- main: single-wave, LDS-double-buffered B via global_load_lds + explicit vmcnt ----------------
__global__ __launch_bounds__(64, 3) void vq_main(const float* __restrict__ X,
                                                 const float* __restrict__ e2h,
                                                 const float* __restrict__ ET,
                                                 const unsigned short* __restrict__ Bpk,
                                                 float* __restrict__ Out) {
    // pool: [0,16384) B double buffer; [16384,16896) e2 double buffer.
    // Epilogue arrays overlap the (dead-by-then) B buffer head.
    __shared__ __align__(16) char lds[16896];
    int*    s_k1  = (int*)(lds);          // [32]
    int*    s_k2  = (int*)(lds + 128);    // [32]
    int*    s_win = (int*)(lds + 256);    // [32]
    double* s_d   = (double*)(lds + 384); // [64]

    const int lane  = threadIdx.x;   // single wave
    const int quad  = lane >> 4;
    const int n16   = lane & 15;
    const int wrow0 = blockIdx.x * 32;

    // ---- A-fragments: 2 m-tiles x 4 k-steps, hi+lo (64 VGPRs)
    bf16x8 ahi[2][4], alo[2][4];
#pragma unroll
    for (int t = 0; t < 2; ++t) {
#pragma unroll
        for (int s = 0; s < 4; ++s) {
            const int row = wrow0 + t * 16 + n16;
            const int d0  = s * 32 + quad * 8;
            const float4 p = *(const float4*)(X + (size_t)row * DD + d0);
            const float4 q = *(const float4*)(X + (size_t)row * DD + d0 + 4);
            float v[8] = {p.x, p.y, p.z, p.w, q.x, q.y, q.z, q.w};
#pragma unroll
            for (int j = 0; j < 8; ++j) {
                unsigned short h = f2bf(v[j]);
                ahi[t][s][j] = (short)h;
                alo[t][s][j] = (short)f2bf(v[j] - bf2f(h));
            }
        }
    }

    // ---- top-2 trackers: positive floats with 6-bit tile id in low mantissa bits
    float p1[2][4], p2[2][4];
#pragma unroll
    for (int t = 0; t < 2; ++t)
#pragma unroll
        for (int r = 0; r < 4; ++r) { p1[t][r] = 0.0f; p2[t][r] = 0.0f; }

    const char* gB = (const char*)Bpk + (size_t)lane * 16;

    auto stage = [&](int nt, int buf) {
        const char* g = gB + (size_t)nt * 8192;
        char* l = lds + buf * 8192;
#pragma unroll
        for (int c = 0; c < 8; ++c)
            gl_lds16(g + c * 1024, l + c * 1024);
        gl_lds4(e2h + nt * 16 + n16, lds + 16384 + buf * 256);
    };

    stage(0, 0);   // 9 VMEM in flight

    for (int nt = 0; nt < NT_COUNT; ++nt) {
        const int cur = nt & 1;
        if (nt + 1 < NT_COUNT) {
            stage(nt + 1, cur ^ 1);                 // 9 newest VMEM
            __builtin_amdgcn_s_waitcnt(3961);       // vmcnt(9): tile nt's 9 complete
        } else {
            __builtin_amdgcn_s_waitcnt(3952);       // vmcnt(0)
        }
        __builtin_amdgcn_sched_barrier(0);

        const char* l = lds + cur * 8192;
        const bf16x8 bh0 = *(const bf16x8*)(l + 0 * 1024 + lane * 16);
        const bf16x8 bh1 = *(const bf16x8*)(l + 1 * 1024 + lane * 16);
        const bf16x8 bh2 = *(const bf16x8*)(l + 2 * 1024 + lane * 16);
        const bf16x8 bh3 = *(const bf16x8*)(l + 3 * 1024 + lane * 16);
        const bf16x8 bl0 = *(const bf16x8*)(l + 4 * 1024 + lane * 16);
        const bf16x8 bl1 = *(const bf16x8*)(l + 5 * 1024 + lane * 16);
        const bf16x8 bl2 = *(const bf16x8*)(l + 6 * 1024 + lane * 16);
        const bf16x8 bl3 = *(const bf16x8*)(l + 7 * 1024 + lane * 16);
        const float  ev  = *(const float*)(lds + 16384 + cur * 256 + lane * 4);
        const unsigned ntinv = (unsigned)(63 - nt);

#pragma unroll
        for (int t = 0; t < 2; ++t) {
            f32x4 acc = {ev, ev, ev, ev};
            acc = __builtin_amdgcn_mfma_f32_16x16x32_bf16(ahi[t][0], bh0, acc, 0, 0, 0);
            acc = __builtin_amdgcn_mfma_f32_16x16x32_bf16(ahi[t][1], bh1, acc, 0, 0, 0);
            acc = __builtin_amdgcn_mfma_f32_16x16x32_bf16(ahi[t][2], bh2, acc, 0, 0, 0);
            acc = __builtin_amdgcn_mfma_f32_16x16x32_bf16(ahi[t][3], bh3, acc, 0, 0, 0);
            acc = __builtin_amdgcn_mfma_f32_16x16x32_bf16(alo[t][0], bh0, acc, 0, 0, 0);
            acc = __builtin_amdgcn_mfma_f32_16x16x32_bf16(alo[t][1], bh1, acc, 0, 0, 0);
            acc = __builtin_amdgcn_mfma_f32_16x16x32_bf16(alo[t][2], bh2, acc, 0, 0, 0);
            acc = __builtin_amdgcn_mfma_f32_16x16x32_bf16(alo[t][3], bh3, acc, 0, 0, 0);
            acc = __builtin_amdgcn_mfma_f32_16x16x32_bf16(ahi[t][0], bl0, acc, 0, 0, 0);
            acc = __builtin_amdgcn_mfma_f32_16x16x32_bf16(ahi[t][1], bl1, acc, 0, 0, 0);
            acc = __builtin_amdgcn_mfma_f32_16x16x32_bf16(ahi[t][2], bl2, acc, 0, 0, 0);
            acc = __builtin_amdgcn_mfma_f32_16x16x32_bf16(ahi[t][3], bl3, acc, 0, 0, 0);
#pragma unroll
            for (int r = 0; r < 4; ++r) {
                float v = __uint_as_float((__float_as_uint(acc[r]) & ~63u) | ntinv);
                float lo = fminf(p1[t][r], v);
                p1[t][r] = fmaxf(p1[t][r], v);
                p2[t][r] = fmaxf(p2[t][r], lo);
            }
        }
    }
    __syncthreads();

    // ---- re-attach full k, merge top-2 across the 16 n-lanes (u64 butterfly)
#pragma unroll
    for (int t = 0; t < 2; ++t) {
#pragma unroll
        for (int r = 0; r < 4; ++r) {
            unsigned u1 = __float_as_uint(p1[t][r]);
            unsigned u2 = __float_as_uint(p2[t][r]);
            int k1 = (int)(63u - (u1 & 63u)) * 16 + n16;
            int k2 = (int)(63u - (u2 & 63u)) * 16 + n16;
            unsigned long long q1 =
                ((unsigned long long)(u1 & ~63u) << 32) | (unsigned)(1023 - k1);
            unsigned long long q2 =
                ((unsigned long long)(u2 & ~63u) << 32) | (unsigned)(1023 - k2);
#pragma unroll
            for (int m = 1; m < 16; m <<= 1) {
                unsigned long long o1 = __shfl_xor(q1, m, 64);
                unsigned long long o2 = __shfl_xor(q2, m, 64);
                unsigned long long lo = q1 < o1 ? q1 : o1;
                q1 = q1 > o1 ? q1 : o1;
                unsigned long long hi2 = q2 > o2 ? q2 : o2;
                q2 = lo > hi2 ? lo : hi2;
            }
            if (n16 == 0) {
                int row = t * 16 + quad * 4 + r;
                s_k1[row] = 1023 - (int)(q1 & 1023u);
                s_k2[row] = 1023 - (int)(q2 & 1023u);
            }
        }
    }
    __syncthreads();

    // ---- fp64 rescore: 32 rows x 2 candidates (dist = e^2 - 2 x.e; x^2 constant/row)
    {
        const int row = lane >> 1;
        const int k   = (lane & 1) ? s_k2[row] : s_k1[row];
        const float* __restrict__ xrow = X + (size_t)(wrow0 + row) * DD;
        const float* __restrict__ erow = ET + (size_t)k * DD;
        double dot = 0.0, ee = 0.0;
#pragma unroll 8
        for (int d = 0; d < DD; ++d) {
            double xv = (double)xrow[d];
            double evd = (double)erow[d];
            dot = fma(xv, evd, dot);
            ee  = fma(evd, evd, ee);
        }
        s_d[lane] = ee - 2.0 * dot;
    }
    __syncthreads();
    if (lane < 32) {
        double d1 = s_d[2 * lane];
        double d2 = s_d[2 * lane + 1];
        int kk1 = s_k1[lane], kk2 = s_k2[lane];
        s_win[lane] = (d2 < d1 || (d2 == d1 && kk2 < kk1)) ? kk2 : kk1;
    }
    __syncthreads();

    // ---- gather winning code rows (exact fp32 copies), coalesced float4
    for (int i = lane; i < 32 * (DD / 4); i += 64) {
        const int row = i >> 5;
        const int d4  = i & 31;
        const float4 v = *(const float4*)(ET + (size_t)s_win[row] * DD + d4 * 4);
        *(float4*)(Out + (size_t)(wrow0 + row) * DD + d4 * 4) = v;
    }
}

extern "C" void kernel_launch(void* const* d_in, const int* in_sizes, int n_in,
                              void* d_out, int out_size, void* d_ws, size_t ws_size,
                              hipStream_t stream) {
    const float* X = (const float*)d_in[0];   // [131072, 128]
    const float* E = (const float*)d_in[1];   // [128, 1024]
    float* Out = (float*)d_out;

    // workspace: e2h (4 KB) | ET (512 KB) | Bpk (512 KB)
    float* e2h = (float*)d_ws;
    float* ET  = e2h + KC;
    unsigned short* Bpk = (unsigned short*)(ET + (size_t)KC * DD);

    const int N = in_sizes[0] / DD;   // 131072

    hipLaunchKernelGGL(vq_prep, dim3(NT_COUNT), dim3(256), 0, stream, E, e2h, ET, Bpk);
    hipLaunchKernelGGL(vq_main, dim3(N / 32), dim3(64), 0, stream,
                       X, e2h, ET, Bpk, Out);
}

// Round 6
// 234.936 us; speedup vs baseline: 2.9212x; 1.0597x over previous
//
#include <hip/hip_runtime.h>

#define KC 1024   // codes
#define DD 128    // dim
#define NT_COUNT (KC / 16)   // 64 code-tiles of 16
#define RPB 64    // rows per block (one wave, 4 m-tiles)

typedef short bf16x8 __attribute__((ext_vector_type(8)));
typedef float f32x4  __attribute__((ext_vector_type(4)));

#define AS1 __attribute__((address_space(1)))
#define AS3 __attribute__((address_space(3)))

static __device__ __forceinline__ unsigned short f2bf(float f) {
    unsigned u = __float_as_uint(f);
    unsigned r = (u + 0x7fffu + ((u >> 16) & 1u)) >> 16;   // RNE
    return (unsigned short)r;
}
static __device__ __forceinline__ float bf2f(unsigned short h) {
    return __uint_as_float(((unsigned)h) << 16);
}
static __device__ __forceinline__ void gl_lds16(const void* g, void* l) {
    __builtin_amdgcn_global_load_lds((const AS1 void*)g, (AS3 void*)l, 16, 0, 0);
}
static __device__ __forceinline__ void gl_lds4(const void* g, void* l) {
    __builtin_amdgcn_global_load_lds((const AS1 void*)g, (AS3 void*)l, 4, 0, 0);
}

// ---------------- fused prep: e2h (+512 offset) + ET + packed bf16 hi/lo B-fragments ----------------
// Bpk byte layout: [nt][c(8)x1024][lane(64)x16]; c<4 = hi s=c, c>=4 = lo s=c-4.
//   element (d,k): d = s*32 + (lane>>4)*8 + j ; k = nt*16 + (lane&15)
__global__ __launch_bounds__(256) void vq_prep(const float* __restrict__ E,
                                               float* __restrict__ e2h,
                                               float* __restrict__ ET,
                                               unsigned short* __restrict__ Bpk) {
    __shared__ float T[16 * 129];   // [k][d]
    const int nt  = blockIdx.x;     // 64 blocks, 16 codes each
    const int tid = threadIdx.x;

    for (int i = tid; i < 16 * DD; i += 256) {
        int d  = i >> 4;
        int kk = i & 15;
        T[kk * 129 + d] = E[(size_t)d * KC + nt * 16 + kk];
    }
    __syncthreads();

    // e2h = 512 - 0.5*||e_k||^2 (offset keeps all screen scores positive)
    if (tid < 16) {
        float s = 0.f;
#pragma unroll 16
        for (int d = 0; d < DD; ++d) {
            float v = T[tid * 129 + d];
            s = fmaf(v, v, s);
        }
        e2h[nt * 16 + tid] = 512.0f - 0.5f * s;
    }

    for (int i = tid; i < 16 * DD; i += 256) {
        int kk = i >> 7;
        int d  = i & 127;
        ET[(size_t)(nt * 16 + kk) * DD + d] = T[kk * 129 + d];
    }

    {
        const int s    = tid >> 6;
        const int lane = tid & 63;
        const int kk   = lane & 15;
        const int d0   = s * 32 + (lane >> 4) * 8;
        bf16x8 hi, lo;
#pragma unroll
        for (int j = 0; j < 8; ++j) {
            float v = T[kk * 129 + d0 + j];
            unsigned short h = f2bf(v);
            hi[j] = (short)h;
            lo[j] = (short)f2bf(v - bf2f(h));
        }
        char* base = (char*)Bpk + (size_t)nt * 8192 + s * 1024 + lane * 16;
        *(bf16x8*)(base)        = hi;
        *(bf16x8*)(base + 4096) = lo;
    }
}

// ---------------- main: single-wave, 64 rows/wave, LDS dbuf via global_load_lds + vmcnt ----------------
// LDS: two buffers, stride 8448: [c(8)x1024 frags][e2 256B]. Epilogue reuses dead buf0 head.
__global__ __launch_bounds__(64, 2) void vq_main(const float* __restrict__ X,
                                                 const float* __restrict__ e2h,
                                                 const float* __restrict__ ET,
                                                 const unsigned short* __restrict__ Bpk,
                                                 float* __restrict__ Out) {
    __shared__ __align__(16) char lds[2 * 8448];
    int* s_k1  = (int*)(lds);          // [64]
    int* s_k2  = (int*)(lds + 256);    // [64]
    int* s_win = (int*)(lds + 512);    // [64]

    const int lane  = threadIdx.x;   // single wave
    const int quad  = lane >> 4;
    const int n16   = lane & 15;
    const int wrow0 = blockIdx.x * RPB;
    const int lidx16 = lane * 16;
    const int lidx4  = lane * 4;

    // ---- A-fragments: 4 m-tiles x 4 k-steps, hi+lo (128 VGPRs)
    bf16x8 ahi[4][4], alo[4][4];
#pragma unroll
    for (int t = 0; t < 4; ++t) {
#pragma unroll
        for (int s = 0; s < 4; ++s) {
            const int row = wrow0 + t * 16 + n16;
            const int d0  = s * 32 + quad * 8;
            const float4 p = *(const float4*)(X + (size_t)row * DD + d0);
            const float4 q = *(const float4*)(X + (size_t)row * DD + d0 + 4);
            float v[8] = {p.x, p.y, p.z, p.w, q.x, q.y, q.z, q.w};
#pragma unroll
            for (int j = 0; j < 8; ++j) {
                unsigned short h = f2bf(v[j]);
                ahi[t][s][j] = (short)h;
                alo[t][s][j] = (short)f2bf(v[j] - bf2f(h));
            }
        }
    }

    // ---- top-2 trackers: positive floats with 6-bit tile id in low mantissa bits
    float p1[4][4], p2[4][4];
#pragma unroll
    for (int t = 0; t < 4; ++t)
#pragma unroll
        for (int r = 0; r < 4; ++r) { p1[t][r] = 0.0f; p2[t][r] = 0.0f; }

#define STAGE(NT, BOFF)                                                          \
    do {                                                                         \
        const char* g = (const char*)Bpk + (size_t)(NT) * 8192;                  \
        _Pragma("unroll")                                                        \
        for (int c = 0; c < 8; ++c)                                              \
            gl_lds16(g + c * 1024 + lidx16, lds + (BOFF) + c * 1024);            \
        gl_lds4(e2h + (NT) * 16 + n16, lds + (BOFF) + 8192);                     \
    } while (0)

#define TILE(NT, BOFF)                                                           \
    do {                                                                         \
        const char* l = lds + (BOFF);                                            \
        const bf16x8 bh0 = *(const bf16x8*)(l + 0 * 1024 + lidx16);              \
        const bf16x8 bh1 = *(const bf16x8*)(l + 1 * 1024 + lidx16);              \
        const bf16x8 bh2 = *(const bf16x8*)(l + 2 * 1024 + lidx16);              \
        const bf16x8 bh3 = *(const bf16x8*)(l + 3 * 1024 + lidx16);              \
        const bf16x8 bl0 = *(const bf16x8*)(l + 4 * 1024 + lidx16);              \
        const bf16x8 bl1 = *(const bf16x8*)(l + 5 * 1024 + lidx16);              \
        const bf16x8 bl2 = *(const bf16x8*)(l + 6 * 1024 + lidx16);              \
        const bf16x8 bl3 = *(const bf16x8*)(l + 7 * 1024 + lidx16);              \
        const float  ev  = *(const float*)(l + 8192 + lidx4);                    \
        const unsigned ntinv = (unsigned)(63 - (NT));                            \
        _Pragma("unroll")                                                        \
        for (int t = 0; t < 4; ++t) {                                            \
            f32x4 acc = {ev, ev, ev, ev};                                        \
            acc = __builtin_amdgcn_mfma_f32_16x16x32_bf16(ahi[t][0], bh0, acc, 0, 0, 0); \
            acc = __builtin_amdgcn_mfma_f32_16x16x32_bf16(ahi[t][1], bh1, acc, 0, 0, 0); \
            acc = __builtin_amdgcn_mfma_f32_16x16x32_bf16(ahi[t][2], bh2, acc, 0, 0, 0); \
            acc = __builtin_amdgcn_mfma_f32_16x16x32_bf16(ahi[t][3], bh3, acc, 0, 0, 0); \
            acc = __builtin_amdgcn_mfma_f32_16x16x32_bf16(alo[t][0], bh0, acc, 0, 0, 0); \
            acc = __builtin_amdgcn_mfma_f32_16x16x32_bf16(alo[t][1], bh1, acc, 0, 0, 0); \
            acc = __builtin_amdgcn_mfma_f32_16x16x32_bf16(alo[t][2], bh2, acc, 0, 0, 0); \
            acc = __builtin_amdgcn_mfma_f32_16x16x32_bf16(alo[t][3], bh3, acc, 0, 0, 0); \
            acc = __builtin_amdgcn_mfma_f32_16x16x32_bf16(ahi[t][0], bl0, acc, 0, 0, 0); \
            acc = __builtin_amdgcn_mfma_f32_16x16x32_bf16(ahi[t][1], bl1, acc, 0, 0, 0); \
            acc = __builtin_amdgcn_mfma_f32_16x16x32_bf16(ahi[t][2], bl2, acc, 0, 0, 0); \
            acc = __builtin_amdgcn_mfma_f32_16x16x32_bf16(ahi[t][3], bl3, acc, 0, 0, 0); \
            _Pragma("unroll")                                                    \
            for (int r = 0; r < 4; ++r) {                                        \
                float v = __uint_as_float((__float_as_uint(acc[r]) & ~63u) | ntinv); \
                float lo = fminf(p1[t][r], v);                                   \
                p1[t][r] = fmaxf(p1[t][r], v);                                   \
                p2[t][r] = fmaxf(p2[t][r], lo);                                  \
            }                                                                    \
        }                                                                        \
    } while (0)

    STAGE(0, 0);
    for (int nt = 0; nt < NT_COUNT; nt += 2) {
        // half A: tile nt in buf0
        STAGE(nt + 1, 8448);
        __builtin_amdgcn_s_waitcnt(3961);       // vmcnt(9): tile nt's 9 complete
        __builtin_amdgcn_sched_barrier(0);
        TILE(nt, 0);
        // half B: tile nt+1 in buf1
        if (nt + 2 < NT_COUNT) {
            STAGE(nt + 2, 0);
            __builtin_amdgcn_s_waitcnt(3961);   // vmcnt(9): tile nt+1's 9 complete
        } else {
            __builtin_amdgcn_s_waitcnt(3952);   // vmcnt(0)
        }
        __builtin_amdgcn_sched_barrier(0);
        TILE(nt + 1, 8448);
    }
#undef STAGE
#undef TILE

    // ---- re-attach full k, merge top-2 across the 16 n-lanes (u64 butterfly)
#pragma unroll
    for (int t = 0; t < 4; ++t) {
#pragma unroll
        for (int r = 0; r < 4; ++r) {
            unsigned u1 = __float_as_uint(p1[t][r]);
            unsigned u2 = __float_as_uint(p2[t][r]);
            int k1 = (int)(63u - (u1 & 63u)) * 16 + n16;
            int k2 = (int)(63u - (u2 & 63u)) * 16 + n16;
            unsigned long long q1 =
                ((unsigned long long)(u1 & ~63u) << 32) | (unsigned)(1023 - k1);
            unsigned long long q2 =
                ((unsigned long long)(u2 & ~63u) << 32) | (unsigned)(1023 - k2);
#pragma unroll
            for (int m = 1; m < 16; m <<= 1) {
                unsigned long long o1 = __shfl_xor(q1, m, 64);
                unsigned long long o2 = __shfl_xor(q2, m, 64);
                unsigned long long lo = q1 < o1 ? q1 : o1;
                q1 = q1 > o1 ? q1 : o1;
                unsigned long long hi2 = q2 > o2 ? q2 : o2;
                q2 = lo > hi2 ? lo : hi2;
            }
            if (n16 == 0) {
                int row = t * 16 + quad * 4 + r;
                s_k1[row] = 1023 - (int)(q1 & 1023u);
                s_k2[row] = 1023 - (int)(q2 & 1023u);
            }
        }
    }
    __syncthreads();

    // ---- fp64 rescore: each lane handles its own row's 2 candidates
    {
        const int k1 = s_k1[lane];
        const int k2 = s_k2[lane];
        const float* __restrict__ xrow = X + (size_t)(wrow0 + lane) * DD;   // L1-hot
        const float* __restrict__ e1 = ET + (size_t)k1 * DD;
        const float* __restrict__ e2p = ET + (size_t)k2 * DD;
        double dot1 = 0.0, ee1 = 0.0, dot2 = 0.0, ee2 = 0.0;
#pragma unroll 4
        for (int d = 0; d < DD; ++d) {
            double xv = (double)xrow[d];
            double v1 = (double)e1[d];
            double v2 = (double)e2p[d];
            dot1 = fma(xv, v1, dot1);
            ee1  = fma(v1, v1, ee1);
            dot2 = fma(xv, v2, dot2);
            ee2  = fma(v2, v2, ee2);
        }
        double d1 = ee1 - 2.0 * dot1;
        double d2 = ee2 - 2.0 * dot2;
        s_win[lane] = (d2 < d1 || (d2 == d1 && k2 < k1)) ? k2 : k1;
    }
    __syncthreads();

    // ---- gather winning code rows (exact fp32 copies), coalesced float4
    for (int i = lane; i < RPB * (DD / 4); i += 64) {
        const int row = i >> 5;
        const int d4  = i & 31;
        const float4 v = *(const float4*)(ET + (size_t)s_win[row] * DD + d4 * 4);
        *(float4*)(Out + (size_t)(wrow0 + row) * DD + d4 * 4) = v;
    }
}

extern "C" void kernel_launch(void* const* d_in, const int* in_sizes, int n_in,
                              void* d_out, int out_size, void* d_ws, size_t ws_size,
                              hipStream_t stream) {
    const float* X = (const float*)d_in[0];   // [131072, 128]
    const float* E = (const float*)d_in[1];   // [128, 1024]
    float* Out = (float*)d_out;

    // workspace: e2h (4 KB) | ET (512 KB) | Bpk (512 KB)
    float* e2h = (float*)d_ws;
    float* ET  = e2h + KC;
    unsigned short* Bpk = (unsigned short*)(ET + (size_t)KC * DD);

    const int N = in_sizes[0] / DD;   // 131072

    hipLaunchKernelGGL(vq_prep, dim3(NT_COUNT), dim3(256), 0, stream, E, e2h, ET, Bpk);
    hipLaunchKernelGGL(vq_main, dim3(N / RPB), dim3(64), 0, stream,
                       X, e2h, ET, Bpk, Out);
}